// Round 1
// baseline (605.206 us; speedup 1.0000x reference)
//
#include <hip/hip_runtime.h>
#include <hip/hip_bf16.h>

// Nearest-neighbor 2x upsample, NHWC fp32.
// x: (B=8, H=128, W=128, C=256) -> out: (8, 256, 256, 256)
// One 64-lane wave per input pixel. lane = c4 (C/4 = 64 float4 per pixel).
// 16B/lane coalesced load; 4 contiguous 1 KiB wave-level stores.

#define B_  8
#define H_  128
#define W_  128
#define C4_ 64    // 256 channels / 4 floats per float4

__global__ __launch_bounds__(256)
void Projector2D_34720515620931_kernel(const float4* __restrict__ in,
                                       float4* __restrict__ out) {
    const int gid  = blockIdx.x * blockDim.x + threadIdx.x;
    const int pix  = gid >> 6;   // global wave id == input pixel id
    const int lane = gid & 63;   // c4 index

    // pix -> (b, h, w), W=128, H=128 (powers of two)
    const int w  = pix & (W_ - 1);
    const int hb = pix >> 7;
    const int h  = hb & (H_ - 1);
    const int b  = hb >> 7;

    const float4 v = in[(size_t)pix * C4_ + lane];

    // output: (b, 2h+dh, 2w+dw, c4) with H2=W2=256
    const size_t row   = (size_t)256 * C4_;                       // one output row of float4
    const size_t base  = (((size_t)b * 256 + 2 * h) * 256 + 2 * w) * C4_ + lane;

    out[base]             = v;   // (2h,   2w)
    out[base + C4_]       = v;   // (2h,   2w+1)
    out[base + row]       = v;   // (2h+1, 2w)
    out[base + row + C4_] = v;   // (2h+1, 2w+1)
}

extern "C" void kernel_launch(void* const* d_in, const int* in_sizes, int n_in,
                              void* d_out, int out_size, void* d_ws, size_t ws_size,
                              hipStream_t stream) {
    const float4* in  = (const float4*)d_in[0];
    float4*       out = (float4*)d_out;

    const int n_pix    = B_ * H_ * W_;       // 131072 input pixels
    const int n_thread = n_pix * 64;         // one wave per pixel
    const int block    = 256;
    const int grid     = n_thread / block;   // 32768, exact

    Projector2D_34720515620931_kernel<<<grid, block, 0, stream>>>(in, out);
}